// Round 5
// baseline (594.647 us; speedup 1.0000x reference)
//
#include <hip/hip_runtime.h>
#include <hip/hip_cooperative_groups.h>
#include <float.h>
#include <math.h>

namespace cg = cooperative_groups;

// AdvancedLossFunction: total = 1.0*occ + 0.1*smooth + 0.01*sparse + 0.1*cons
// Single cooperative kernel, 4 phases separated by grid.sync():
//   p1: tj[j]=(-2x,-2y,-2z,|q|^2) + BCE/cons/sparse partial sums (atomics after sync1)
//   p2: thresh_i = 3rd-smallest t over 1024-sample subset  (t = -2 p.q + |q|^2)
//   p3: threshold-pruned brute-force scan, __any()-gated insert (rare branch)
//   p4: merge per-chunk top-3s, smoothness sum, finalize out[0]
// Same fmaf chain in p2/p3 -> bit-identical t -> exact threshold semantics.

constexpr int   N_ = 16384;
constexpr int   F_ = 64;
constexpr float OCC_W = 1.0f, SMOOTH_W = 0.1f, SPARSE_W = 0.01f, CONS_W = 0.1f;
constexpr float EPS_ = 1e-7f;

// ws layout:
//   0        : float acc[4] {occ, cons, sparse, smooth}   (zeroed in-kernel)
//   256      : float4 tj[N]
//   +N*16    : float thresh[N]
//   +N*4     : float2 cand[CHUNKS*3][N]  (t, pred_of_neighbor)

__device__ __forceinline__ float tdist(float px, float py, float pz, float4 q) {
  return fmaf(px, q.x, fmaf(py, q.y, fmaf(pz, q.z, q.w)));
}

template <int CHUNKS>
__global__ __launch_bounds__(256, 8) void fused_kernel(const float* __restrict__ pred,
                                                       const float* __restrict__ targ,
                                                       const float* __restrict__ feat,
                                                       const float* __restrict__ pts,
                                                       float* __restrict__ acc,
                                                       float4* __restrict__ tj,
                                                       float* __restrict__ thresh,
                                                       float2* __restrict__ cand,
                                                       float* __restrict__ out) {
  constexpr int GRID  = 16 * CHUNKS;
  constexpr int NTHR  = GRID * 256;
  constexpr int CHUNK = N_ / CHUNKS;
  constexpr int TILE  = (CHUNK < 1024) ? CHUNK : 1024;
  constexpr int IPB   = N_ / GRID;          // i's per block in p2/p4 (8 at GRID=2048)
  constexpr int TPI   = 256 / IPB;          // threads per i (32)
  constexpr int SPT   = 1024 / TPI;         // samples per thread (32)
  constexpr size_t SM = ((size_t)TILE * 20 > 6144) ? (size_t)TILE * 20 : 6144;
  __shared__ __align__(16) char smem[SM];

  cg::grid_group gg = cg::this_grid();
  const int tid  = threadIdx.x;
  const int gtid = blockIdx.x * 256 + tid;

  // ---------------- phase 1: tj + scalar partial sums ----------------
  float s_sp = 0.f;
  const float4* f4 = (const float4*)feat;
  for (int t = gtid; t < N_ * F_ / 4; t += NTHR) {
    float4 v = f4[t];
    s_sp += fabsf(v.x) + fabsf(v.y) + fabsf(v.z) + fabsf(v.w);
  }
  float s_occ = 0.f, s_cons = 0.f;
  for (int i = gtid; i < N_; i += NTHR) {
    float pr = pred[i], tg = targ[i];
    float p  = fminf(fmaxf(pr, EPS_), 1.0f - EPS_);
    s_occ  -= tg * __logf(p) + (1.0f - tg) * __logf(1.0f - p);
    float d = pr - tg;
    s_cons += d * d;
    float x = pts[3 * i], y = pts[3 * i + 1], z = pts[3 * i + 2];
    tj[i] = make_float4(-2.f * x, -2.f * y, -2.f * z, fmaf(x, x, fmaf(y, y, z * z)));
  }
  for (int off = 32; off > 0; off >>= 1) {
    s_sp   += __shfl_down(s_sp, off);
    s_occ  += __shfl_down(s_occ, off);
    s_cons += __shfl_down(s_cons, off);
  }
  {
    float* wred = (float*)smem;             // [4 waves][3]
    if ((tid & 63) == 0) {
      int w = tid >> 6;
      wred[w * 3] = s_occ; wred[w * 3 + 1] = s_cons; wred[w * 3 + 2] = s_sp;
    }
    __syncthreads();
    if (tid == 0) {
      s_occ = wred[0] + wred[3] + wred[6] + wred[9];
      s_cons = wred[1] + wred[4] + wred[7] + wred[10];
      s_sp  = wred[2] + wred[5] + wred[8] + wred[11];
    }
  }
  if (gtid == 0) { acc[0] = 0.f; acc[1] = 0.f; acc[2] = 0.f; acc[3] = 0.f; }

  gg.sync();   // sync1: tj complete, acc zeroed

  if (tid == 0) {
    atomicAdd(&acc[0], s_occ);
    atomicAdd(&acc[1], s_cons);
    atomicAdd(&acc[2], s_sp);
  }

  // ---------------- phase 2: thresh via 1024-point sample ----------------
  {
    int i_local = tid % IPB;
    int sub     = tid / IPB;
    int i = blockIdx.x * IPB + i_local;
    float4 ti = tj[i];
    float px = -0.5f * ti.x, py = -0.5f * ti.y, pz = -0.5f * ti.z;
    float b0 = FLT_MAX, b1 = FLT_MAX, b2 = FLT_MAX;
    int base = i + 1 + 16 * (sub * SPT);    // j = (i + 1 + 16k) mod N, never self
#pragma unroll 8
    for (int s = 0; s < SPT; ++s) {
      int j = (base + 16 * s) & (N_ - 1);   // octet-coalesced: 8 consecutive i per lane-octet
      float t = tdist(px, py, pz, tj[j]);
      float n0 = fminf(b0, t);
      float n1 = fminf(b1, fmaxf(b0, t));
      float n2 = fminf(b2, fmaxf(b1, t));
      b0 = n0; b1 = n1; b2 = n2;
    }
    float* sh = (float*)smem;               // [256][3]
    sh[tid * 3] = b0; sh[tid * 3 + 1] = b1; sh[tid * 3 + 2] = b2;
    __syncthreads();
    for (int st = TPI >> 1; st > 0; st >>= 1) {
      if (sub < st) {
        int o = ((sub + st) * IPB + i_local) * 3;
#pragma unroll
        for (int m = 0; m < 3; ++m) {
          float t = sh[o + m];
          float n0 = fminf(b0, t);
          float n1 = fminf(b1, fmaxf(b0, t));
          float n2 = fminf(b2, fmaxf(b1, t));
          b0 = n0; b1 = n1; b2 = n2;
        }
        sh[tid * 3] = b0; sh[tid * 3 + 1] = b1; sh[tid * 3 + 2] = b2;
      }
      __syncthreads();
    }
    if (sub == 0) thresh[i] = b2;
  }

  gg.sync();   // sync2: thresh complete

  // ---------------- phase 3: pruned brute-force 3-NN ----------------
  {
    constexpr int ITEMS = 4, IPG = 1024, IGROUPS = 16;
    int igrp  = blockIdx.x % IGROUPS;
    int chunk = blockIdx.x / IGROUPS;
    int j0    = chunk * CHUNK;
    float4* tile  = (float4*)smem;
    float*  tilep = (float*)(smem + (size_t)TILE * 16);

    int   idx[ITEMS];
    float px[ITEMS], py[ITEMS], pz[ITEMS], th[ITEMS];
    float b0[ITEMS], b1[ITEMS], b2[ITEMS];
    float q0[ITEMS], q1[ITEMS], q2[ITEMS];
#pragma unroll
    for (int k = 0; k < ITEMS; ++k) {
      int i = igrp * IPG + tid + k * 256;
      idx[k] = i;
      float4 ti = tj[i];
      px[k] = -0.5f * ti.x; py[k] = -0.5f * ti.y; pz[k] = -0.5f * ti.z;
      th[k] = thresh[i];
      b0[k] = b1[k] = b2[k] = FLT_MAX;
      q0[k] = q1[k] = q2[k] = 0.f;
    }

    for (int sub = 0; sub < CHUNK; sub += TILE) {
      __syncthreads();
      for (int t = tid; t < TILE; t += 256) {
        tile[t]  = tj[j0 + sub + t];
        tilep[t] = pred[j0 + sub + t];
      }
      __syncthreads();
      int jg0 = j0 + sub;
#pragma unroll 4
      for (int jj = 0; jj < TILE; ++jj) {
        float4 c4 = tile[jj];               // wave-uniform -> LDS broadcast
        int jg = jg0 + jj;
#pragma unroll
        for (int k = 0; k < ITEMS; ++k) {
          float t = tdist(px[k], py[k], pz[k], c4);
          bool hit = (t <= th[k]);
          if (__any(hit)) {                 // uniform branch: body skipped ~85-90% of gates
            if (hit && jg != idx[k]) {
              float qw = tilep[jj];
              bool cc0 = t < b0[k], cc1 = t < b1[k], cc2 = t < b2[k];
              if (cc2) {
                float nb2 = cc1 ? b1[k] : t;                  float nq2 = cc1 ? q1[k] : qw;
                float nb1 = cc0 ? b0[k] : (cc1 ? t : b1[k]);  float nq1 = cc0 ? q0[k] : (cc1 ? qw : q1[k]);
                float nb0 = cc0 ? t : b0[k];                  float nq0 = cc0 ? qw : q0[k];
                b0[k] = nb0; b1[k] = nb1; b2[k] = nb2;
                q0[k] = nq0; q1[k] = nq1; q2[k] = nq2;
              }
            }
          }
        }
      }
    }
#pragma unroll
    for (int k = 0; k < ITEMS; ++k) {
      cand[((size_t)chunk * 3 + 0) * N_ + idx[k]] = make_float2(b0[k], q0[k]);
      cand[((size_t)chunk * 3 + 1) * N_ + idx[k]] = make_float2(b1[k], q1[k]);
      cand[((size_t)chunk * 3 + 2) * N_ + idx[k]] = make_float2(b2[k], q2[k]);
    }
  }

  gg.sync();   // sync3: cand complete

  // ---------------- phase 4: merge + smoothness + finalize ----------------
  {
    constexpr int CPT = CHUNKS / TPI;       // chunks per thread (4)
    int i_local = tid % IPB;
    int sub     = tid / IPB;
    int i = blockIdx.x * IPB + i_local;
    float b0 = FLT_MAX, b1 = FLT_MAX, b2 = FLT_MAX;
    float q0 = 0.f, q1 = 0.f, q2 = 0.f;
    auto ins = [&](float t, float qw) {
      if (t < b2) {
        bool cc0 = t < b0, cc1 = t < b1;
        float nb2 = cc1 ? b1 : t;               float nq2 = cc1 ? q1 : qw;
        float nb1 = cc0 ? b0 : (cc1 ? t : b1);  float nq1 = cc0 ? q0 : (cc1 ? qw : q1);
        float nb0 = cc0 ? t : b0;               float nq0 = cc0 ? qw : q0;
        b0 = nb0; b1 = nb1; b2 = nb2; q0 = nq0; q1 = nq1; q2 = nq2;
      }
    };
    for (int cc = 0; cc < CPT; ++cc) {
      int c = sub * CPT + cc;
      const float2* basep = cand + (size_t)c * 3 * N_;
#pragma unroll
      for (int m = 0; m < 3; ++m) {
        float2 v = basep[(size_t)m * N_ + i]; // lane-octets: 8 consecutive i -> 64B segs
        ins(v.x, v.y);
      }
    }
    float2* sh2 = (float2*)smem;              // [256][3]
    sh2[tid * 3]     = make_float2(b0, q0);
    sh2[tid * 3 + 1] = make_float2(b1, q1);
    sh2[tid * 3 + 2] = make_float2(b2, q2);
    __syncthreads();
    for (int st = TPI >> 1; st > 0; st >>= 1) {
      if (sub < st) {
        int o = ((sub + st) * IPB + i_local) * 3;
#pragma unroll
        for (int m = 0; m < 3; ++m) { float2 v = sh2[o + m]; ins(v.x, v.y); }
        sh2[tid * 3]     = make_float2(b0, q0);
        sh2[tid * 3 + 1] = make_float2(b1, q1);
        sh2[tid * 3 + 2] = make_float2(b2, q2);
      }
      __syncthreads();
    }
    float s = 0.f;
    if (sub == 0) {
      float pi = pred[i];
      s = fabsf(pi - q0) + fabsf(pi - q1) + fabsf(pi - q2);
    }
    // sub==0  <=>  tid < IPB (<=32): all in wave 0
    for (int off = IPB >> 1; off > 0; off >>= 1) s += __shfl_down(s, off);
    if (tid == 0) atomicAdd(&acc[3], s);
  }

  gg.sync();   // sync4: all sums complete

  if (gtid == 0) {
    float occ  = atomicAdd(&acc[0], 0.f);
    float cons = atomicAdd(&acc[1], 0.f);
    float sp   = atomicAdd(&acc[2], 0.f);
    float sm   = atomicAdd(&acc[3], 0.f);
    out[0] = OCC_W * (occ / (float)N_)
           + CONS_W * (cons / (float)N_)
           + SPARSE_W * (sp / (float)(N_ * F_))
           + SMOOTH_W * (sm / (float)(N_ * 3));
  }
}

extern "C" void kernel_launch(void* const* d_in, const int* in_sizes, int n_in,
                              void* d_out, int out_size, void* d_ws, size_t ws_size,
                              hipStream_t stream) {
  const float* pred = (const float*)d_in[0];
  const float* targ = (const float*)d_in[1];
  const float* feat = (const float*)d_in[2];
  const float* pts  = (const float*)d_in[3];
  float* out = (float*)d_out;

  char*   ws     = (char*)d_ws;
  float*  acc    = (float*)ws;
  float4* tj     = (float4*)(ws + 256);
  float*  thresh = (float*)(ws + 256 + (size_t)N_ * 16);
  float2* cand   = (float2*)(ws + 256 + (size_t)N_ * 16 + (size_t)N_ * 4);

  size_t base = 256 + (size_t)N_ * 16 + (size_t)N_ * 4;
  auto need = [&](int c) { return base + (size_t)c * 3 * N_ * sizeof(float2); };

  int numCU = 256;
  hipDeviceGetAttribute(&numCU, hipDeviceAttributeMultiprocessorCount, 0);
  int occ128 = 0, occ64 = 0;
  hipOccupancyMaxActiveBlocksPerMultiprocessor(&occ128, fused_kernel<128>, 256, 0);
  hipOccupancyMaxActiveBlocksPerMultiprocessor(&occ64,  fused_kernel<64>,  256, 0);

  void* args[] = {(void*)&pred, (void*)&targ, (void*)&feat, (void*)&pts,
                  (void*)&acc, (void*)&tj, (void*)&thresh, (void*)&cand, (void*)&out};

  if (ws_size >= need(128) && (size_t)occ128 * numCU >= 2048) {
    hipLaunchCooperativeKernel((void*)fused_kernel<128>, dim3(2048), dim3(256), args, 0, stream);
  } else if (ws_size >= need(64) && (size_t)occ64 * numCU >= 1024) {
    hipLaunchCooperativeKernel((void*)fused_kernel<64>, dim3(1024), dim3(256), args, 0, stream);
  } else {
    hipLaunchCooperativeKernel((void*)fused_kernel<32>, dim3(512), dim3(256), args, 0, stream);
  }
}

// Round 6
// 360.778 us; speedup vs baseline: 1.6482x; 1.6482x over previous
//
#include <hip/hip_runtime.h>
#include <float.h>
#include <math.h>

// AdvancedLossFunction: total = 1.0*occ + 0.1*smooth + 0.01*sparse + 0.1*cons
// 3-NN via threshold-pruned brute force (4 dispatches; cooperative fusion regressed 3x in R5):
//   t(i,j) = d2(i,j) - |p_i|^2 = -2 p_i.q_j + |q_j|^2  (monotone in d2 for fixed i)
//   sample: thresh_i = 4th-smallest t over fixed set S={8k} (2048 pts). 4th >= 3rd-excl-self
//           even when i in S (self is the strict minimum) -> provably safe upper bound.
//   knn:    full scan, __any()-gated insert when t <= thresh_i (~32 exp. hits/i)
//   Same fmaf chain in both passes -> bit-identical t -> exact threshold semantics.

constexpr int   N_ = 16384;
constexpr int   F_ = 64;
constexpr float OCC_W = 1.0f, SMOOTH_W = 0.1f, SPARSE_W = 0.01f, CONS_W = 0.1f;
constexpr float EPS_ = 1e-7f;

// ws layout:
//   0          : float acc[4] {occ, cons, sparse, smooth}
//   16         : unsigned done
//   256        : float4 tj[N]      (-2x, -2y, -2z, |q|^2)
//   256+N*16   : float thresh[N]
//   +N*4       : float2 cand[CHUNKS*3][N]  (t, pred_of_neighbor)

__device__ __forceinline__ float tdist(float px, float py, float pz, float4 q) {
  return fmaf(px, q.x, fmaf(py, q.y, fmaf(pz, q.z, q.w)));
}

__device__ __forceinline__ void ins4(float t, float& b0, float& b1, float& b2, float& b3) {
  float n0 = fminf(b0, t);
  float n1 = fminf(b1, fmaxf(b0, t));
  float n2 = fminf(b2, fmaxf(b1, t));
  float n3 = fminf(b3, fmaxf(b2, t));
  b0 = n0; b1 = n1; b2 = n2; b3 = n3;
}

__global__ __launch_bounds__(256) void reduce_tj_kernel(const float* __restrict__ pred,
                                                        const float* __restrict__ targ,
                                                        const float* __restrict__ feat,
                                                        const float* __restrict__ pts,
                                                        float* __restrict__ acc,
                                                        float4* __restrict__ tj) {
  int gtid = blockIdx.x * 256 + threadIdx.x;       // grid 1024 -> 262144 = N*F/4 threads
  float4 v = ((const float4*)feat)[gtid];          // exactly one float4 each
  float s_sp = fabsf(v.x) + fabsf(v.y) + fabsf(v.z) + fabsf(v.w);
  float s_occ = 0.f, s_cons = 0.f;
  if (gtid < N_) {
    float pr = pred[gtid], tg = targ[gtid];
    float p  = fminf(fmaxf(pr, EPS_), 1.0f - EPS_);
    s_occ = -(tg * __logf(p) + (1.0f - tg) * __logf(1.0f - p));
    float d = pr - tg;
    s_cons = d * d;
    float x = pts[3 * gtid], y = pts[3 * gtid + 1], z = pts[3 * gtid + 2];
    tj[gtid] = make_float4(-2.f * x, -2.f * y, -2.f * z, fmaf(x, x, fmaf(y, y, z * z)));
  }
  for (int off = 32; off > 0; off >>= 1) {
    s_sp   += __shfl_down(s_sp, off);
    s_occ  += __shfl_down(s_occ, off);
    s_cons += __shfl_down(s_cons, off);
  }
  if ((threadIdx.x & 63) == 0) {
    atomicAdd(&acc[0], s_occ);
    atomicAdd(&acc[1], s_cons);
    atomicAdd(&acc[2], s_sp);
  }
}

// thresh_i = 4th-smallest t over S = {8u : u=0..2047}. 16 threads/i, 128 samples each.
// Within each 16-lane group all lanes read the SAME tj[j] -> HW broadcast, L2-resident.
__global__ __launch_bounds__(256) void sample_kernel(const float4* __restrict__ tj,
                                                     float* __restrict__ thresh) {
  __shared__ float sh[256 * 4];
  int i_local = threadIdx.x & 15;
  int sub     = threadIdx.x >> 4;                  // 0..15
  int i = blockIdx.x * 16 + i_local;               // grid 1024 -> 4 blocks/CU
  float4 ti = tj[i];
  float px = -0.5f * ti.x, py = -0.5f * ti.y, pz = -0.5f * ti.z;  // exact
  float b0 = FLT_MAX, b1 = FLT_MAX, b2 = FLT_MAX, b3 = FLT_MAX;
#pragma unroll 8
  for (int s = 0; s < 128; ++s) {
    int j = 8 * (sub * 128 + s);                   // i-independent sample set
    float t = tdist(px, py, pz, tj[j]);
    ins4(t, b0, b1, b2, b3);
  }
  sh[threadIdx.x * 4 + 0] = b0; sh[threadIdx.x * 4 + 1] = b1;
  sh[threadIdx.x * 4 + 2] = b2; sh[threadIdx.x * 4 + 3] = b3;
  __syncthreads();
  for (int st = 8; st > 0; st >>= 1) {
    if (sub < st) {
      int o = ((sub + st) * 16 + i_local) * 4;
#pragma unroll
      for (int m = 0; m < 4; ++m) ins4(sh[o + m], b0, b1, b2, b3);
      sh[threadIdx.x * 4 + 0] = b0; sh[threadIdx.x * 4 + 1] = b1;
      sh[threadIdx.x * 4 + 2] = b2; sh[threadIdx.x * 4 + 3] = b3;
    }
    __syncthreads();
  }
  if (sub == 0) thresh[i] = b3;                    // 4th smallest
}

template <int CHUNKS>
__global__ __launch_bounds__(256) void knn_kernel(const float4* __restrict__ tj,
                                                  const float* __restrict__ pred,
                                                  const float* __restrict__ thresh,
                                                  float2* __restrict__ cand) {
  constexpr int CHUNK   = N_ / CHUNKS;             // 256 at CHUNKS=64
  constexpr int ITEMS   = 4;
  constexpr int IPG     = 1024;
  constexpr int IGROUPS = N_ / IPG;                // 16
  constexpr int TILE    = (CHUNK < 1024) ? CHUNK : 1024;

  int igrp  = blockIdx.x % IGROUPS;
  int chunk = blockIdx.x / IGROUPS;
  int j0    = chunk * CHUNK;

  __shared__ float4 tile[TILE];
  __shared__ float  tilep[TILE];

  int   idx[ITEMS];
  float px[ITEMS], py[ITEMS], pz[ITEMS], th[ITEMS];
  float b0[ITEMS], b1[ITEMS], b2[ITEMS];
  float q0[ITEMS], q1[ITEMS], q2[ITEMS];
#pragma unroll
  for (int k = 0; k < ITEMS; ++k) {
    int i = igrp * IPG + threadIdx.x + k * 256;
    idx[k] = i;
    float4 ti = tj[i];
    px[k] = -0.5f * ti.x; py[k] = -0.5f * ti.y; pz[k] = -0.5f * ti.z;
    th[k] = thresh[i];
    b0[k] = b1[k] = b2[k] = FLT_MAX;
    q0[k] = q1[k] = q2[k] = 0.f;
  }

  for (int sub = 0; sub < CHUNK; sub += TILE) {
    __syncthreads();
    for (int t = threadIdx.x; t < TILE; t += 256) {
      tile[t]  = tj[j0 + sub + t];
      tilep[t] = pred[j0 + sub + t];
    }
    __syncthreads();
    int jg0 = j0 + sub;
#pragma unroll 4
    for (int jj = 0; jj < TILE; ++jj) {
      float4 c4 = tile[jj];                        // wave-uniform -> LDS broadcast
      int jg = jg0 + jj;
#pragma unroll
      for (int k = 0; k < ITEMS; ++k) {
        float t = tdist(px[k], py[k], pz[k], c4);
        bool hit = (t <= th[k]);
        if (__any(hit)) {                          // ~12% taken -> real wave-level skip
          if (hit && jg != idx[k]) {
            float qw = tilep[jj];
            bool cc0 = t < b0[k], cc1 = t < b1[k], cc2 = t < b2[k];
            if (cc2) {
              float nb2 = cc1 ? b1[k] : t;                  float nq2 = cc1 ? q1[k] : qw;
              float nb1 = cc0 ? b0[k] : (cc1 ? t : b1[k]);  float nq1 = cc0 ? q0[k] : (cc1 ? qw : q1[k]);
              float nb0 = cc0 ? t : b0[k];                  float nq0 = cc0 ? qw : q0[k];
              b0[k] = nb0; b1[k] = nb1; b2[k] = nb2;
              q0[k] = nq0; q1[k] = nq1; q2[k] = nq2;
            }
          }
        }
      }
    }
  }

#pragma unroll
  for (int k = 0; k < ITEMS; ++k) {
    cand[((size_t)chunk * 3 + 0) * N_ + idx[k]] = make_float2(b0[k], q0[k]);
    cand[((size_t)chunk * 3 + 1) * N_ + idx[k]] = make_float2(b1[k], q1[k]);
    cand[((size_t)chunk * 3 + 2) * N_ + idx[k]] = make_float2(b2[k], q2[k]);
  }
}

// 16 i's per block, 16 threads per i; LDS tree merge; ticket finalize. grid 1024.
__global__ __launch_bounds__(256) void merge_finalize_kernel(const float* __restrict__ pred,
                                                             const float2* __restrict__ cand,
                                                             int chunks,
                                                             float* __restrict__ acc,
                                                             unsigned* __restrict__ done,
                                                             float* __restrict__ out) {
  __shared__ float2 sh[256 * 3];
  int i_local = threadIdx.x & 15;
  int sub     = threadIdx.x >> 4;                  // 0..15
  int i = blockIdx.x * 16 + i_local;

  float b0 = FLT_MAX, b1 = FLT_MAX, b2 = FLT_MAX;
  float q0 = 0.f, q1 = 0.f, q2 = 0.f;
  auto ins = [&](float t, float qw) {
    if (t < b2) {
      bool cc0 = t < b0, cc1 = t < b1;
      float nb2 = cc1 ? b1 : t;               float nq2 = cc1 ? q1 : qw;
      float nb1 = cc0 ? b0 : (cc1 ? t : b1);  float nq1 = cc0 ? q0 : (cc1 ? qw : q1);
      float nb0 = cc0 ? t : b0;               float nq0 = cc0 ? qw : q0;
      b0 = nb0; b1 = nb1; b2 = nb2; q0 = nq0; q1 = nq1; q2 = nq2;
    }
  };
  int cpt = chunks >> 4;                           // chunks per thread
  for (int cc = 0; cc < cpt; ++cc) {
    int c = sub * cpt + cc;
    const float2* basep = cand + (size_t)c * 3 * N_;
#pragma unroll
    for (int m = 0; m < 3; ++m) {
      float2 v = basep[(size_t)m * N_ + i];        // 16 consecutive i -> 128B segments
      ins(v.x, v.y);
    }
  }
  sh[threadIdx.x * 3 + 0] = make_float2(b0, q0);
  sh[threadIdx.x * 3 + 1] = make_float2(b1, q1);
  sh[threadIdx.x * 3 + 2] = make_float2(b2, q2);
  __syncthreads();
  for (int st = 8; st > 0; st >>= 1) {
    if (sub < st) {
      int o = ((sub + st) * 16 + i_local) * 3;
#pragma unroll
      for (int m = 0; m < 3; ++m) { float2 v = sh[o + m]; ins(v.x, v.y); }
      sh[threadIdx.x * 3 + 0] = make_float2(b0, q0);
      sh[threadIdx.x * 3 + 1] = make_float2(b1, q1);
      sh[threadIdx.x * 3 + 2] = make_float2(b2, q2);
    }
    __syncthreads();
  }

  float s = 0.f;
  if (sub == 0) {                                  // tid < 16, all in wave 0
    float pi = pred[i];
    s = fabsf(pi - q0) + fabsf(pi - q1) + fabsf(pi - q2);
  }
  if (threadIdx.x < 64) {
    for (int off = 8; off > 0; off >>= 1) s += __shfl_down(s, off);
    if (threadIdx.x == 0) {
      atomicAdd(&acc[3], s);
      __threadfence();
      unsigned prev = atomicAdd(done, 1u);
      if (prev == (unsigned)(gridDim.x - 1)) {
        float occ  = atomicAdd(&acc[0], 0.f);
        float cons = atomicAdd(&acc[1], 0.f);
        float sp   = atomicAdd(&acc[2], 0.f);
        float sm   = atomicAdd(&acc[3], 0.f);
        out[0] = OCC_W * (occ / (float)N_)
               + CONS_W * (cons / (float)N_)
               + SPARSE_W * (sp / (float)(N_ * F_))
               + SMOOTH_W * (sm / (float)(N_ * 3));
      }
    }
  }
}

extern "C" void kernel_launch(void* const* d_in, const int* in_sizes, int n_in,
                              void* d_out, int out_size, void* d_ws, size_t ws_size,
                              hipStream_t stream) {
  const float* pred = (const float*)d_in[0];
  const float* targ = (const float*)d_in[1];
  const float* feat = (const float*)d_in[2];
  const float* pts  = (const float*)d_in[3];
  float* out = (float*)d_out;

  char*     ws     = (char*)d_ws;
  float*    acc    = (float*)ws;
  unsigned* done   = (unsigned*)(ws + 16);
  float4*   tj     = (float4*)(ws + 256);
  float*    thresh = (float*)(ws + 256 + (size_t)N_ * 16);
  float2*   cand   = (float2*)(ws + 256 + (size_t)N_ * 16 + (size_t)N_ * 4);

  hipMemsetAsync(ws, 0, 256, stream);

  reduce_tj_kernel<<<1024, 256, 0, stream>>>(pred, targ, feat, pts, acc, tj);
  sample_kernel<<<1024, 256, 0, stream>>>(tj, thresh);

  size_t base = 256 + (size_t)N_ * 16 + (size_t)N_ * 4;
  auto need = [&](int c) { return base + (size_t)c * 3 * N_ * sizeof(float2); };
  int chunks;
  if      (ws_size >= need(64)) chunks = 64;
  else if (ws_size >= need(32)) chunks = 32;
  else                          chunks = 16;

  if (chunks == 64)      knn_kernel<64><<<16 * 64, 256, 0, stream>>>(tj, pred, thresh, cand);
  else if (chunks == 32) knn_kernel<32><<<16 * 32, 256, 0, stream>>>(tj, pred, thresh, cand);
  else                   knn_kernel<16><<<16 * 16, 256, 0, stream>>>(tj, pred, thresh, cand);

  merge_finalize_kernel<<<1024, 256, 0, stream>>>(pred, cand, chunks, acc, done, out);
}

// Round 7
// 173.681 us; speedup vs baseline: 3.4238x; 2.0772x over previous
//
#include <hip/hip_runtime.h>
#include <float.h>
#include <math.h>

// AdvancedLossFunction: total = 1.0*occ + 0.1*smooth + 0.01*sparse + 0.1*cons
// 3-NN via threshold-pruned brute force. 5 dispatches, ZERO contended atomics
// (R6 lesson: same-line device atomicAdd ~13ns serialized; 12k of them = 158us).
//   t(i,j) = d2(i,j) - |p_i|^2 = -2 p_i.q_j + |q_j|^2  (monotone in d2 for fixed i)
//   sample: thresh_i = 4th-smallest t over fixed set S={8u} (2048 pts); 4th-smallest
//           >= 3rd-smallest-excluding-self even when i in S -> provably safe bound.
//   knn:    full scan, __any()-gated insert when t <= thresh_i
//   Same fmaf chain in both passes -> bit-identical t -> exact threshold semantics.

constexpr int   N_ = 16384;
constexpr int   F_ = 64;
constexpr float OCC_W = 1.0f, SMOOTH_W = 0.1f, SPARSE_W = 0.01f, CONS_W = 0.1f;
constexpr float EPS_ = 1e-7f;

// ws layout:
//   0      : float pA[3][256]   (occ/cons/sparse per-block partials, NO atomics)
//   3072   : float pS[1024]     (smoothness per-block partials)
//   8192   : float4 tj[N]       (-2x,-2y,-2z,|q|^2)
//   +N*16  : float thresh[N]
//   +N*4   : float2 cand[CHUNKS*3][N]   (t, pred_of_neighbor)

__device__ __forceinline__ float tdist(float px, float py, float pz, float4 q) {
  return fmaf(px, q.x, fmaf(py, q.y, fmaf(pz, q.z, q.w)));
}

__device__ __forceinline__ void ins4(float t, float& b0, float& b1, float& b2, float& b3) {
  float n0 = fminf(b0, t);
  float n1 = fminf(b1, fmaxf(b0, t));
  float n2 = fminf(b2, fmaxf(b1, t));
  float n3 = fminf(b3, fmaxf(b2, t));
  b0 = n0; b1 = n1; b2 = n2; b3 = n3;
}

// grid 256. Per-block partials to distinct addresses; zero atomics.
__global__ __launch_bounds__(256) void reduce_tj_kernel(const float* __restrict__ pred,
                                                        const float* __restrict__ targ,
                                                        const float* __restrict__ feat,
                                                        const float* __restrict__ pts,
                                                        float* __restrict__ pA,
                                                        float4* __restrict__ tj) {
  __shared__ float wred[4][3];
  int gtid = blockIdx.x * 256 + threadIdx.x;       // 65536 threads
  float s_sp = 0.f;
  const float4* f4 = (const float4*)feat;
#pragma unroll
  for (int t = gtid; t < N_ * F_ / 4; t += 65536) { // 4 coalesced iters
    float4 v = f4[t];
    s_sp += fabsf(v.x) + fabsf(v.y) + fabsf(v.z) + fabsf(v.w);
  }
  float s_occ = 0.f, s_cons = 0.f;
  if (gtid < N_) {
    float pr = pred[gtid], tg = targ[gtid];
    float p  = fminf(fmaxf(pr, EPS_), 1.0f - EPS_);
    s_occ = -(tg * __logf(p) + (1.0f - tg) * __logf(1.0f - p));
    float d = pr - tg;
    s_cons = d * d;
    float x = pts[3 * gtid], y = pts[3 * gtid + 1], z = pts[3 * gtid + 2];
    tj[gtid] = make_float4(-2.f * x, -2.f * y, -2.f * z, fmaf(x, x, fmaf(y, y, z * z)));
  }
  for (int off = 32; off > 0; off >>= 1) {
    s_sp   += __shfl_down(s_sp, off);
    s_occ  += __shfl_down(s_occ, off);
    s_cons += __shfl_down(s_cons, off);
  }
  if ((threadIdx.x & 63) == 0) {
    int w = threadIdx.x >> 6;
    wred[w][0] = s_occ; wred[w][1] = s_cons; wred[w][2] = s_sp;
  }
  __syncthreads();
  if (threadIdx.x == 0) {
    pA[0 * 256 + blockIdx.x] = wred[0][0] + wred[1][0] + wred[2][0] + wred[3][0];
    pA[1 * 256 + blockIdx.x] = wred[0][1] + wred[1][1] + wred[2][1] + wred[3][1];
    pA[2 * 256 + blockIdx.x] = wred[0][2] + wred[1][2] + wred[2][2] + wred[3][2];
  }
}

// thresh_i = 4th-smallest t over S = {8u}. 16 threads/i, 128 samples each. grid 1024.
__global__ __launch_bounds__(256) void sample_kernel(const float4* __restrict__ tj,
                                                     float* __restrict__ thresh) {
  __shared__ float sh[256 * 4];
  int i_local = threadIdx.x & 15;
  int sub     = threadIdx.x >> 4;
  int i = blockIdx.x * 16 + i_local;
  float4 ti = tj[i];
  float px = -0.5f * ti.x, py = -0.5f * ti.y, pz = -0.5f * ti.z;  // exact
  float b0 = FLT_MAX, b1 = FLT_MAX, b2 = FLT_MAX, b3 = FLT_MAX;
#pragma unroll 8
  for (int s = 0; s < 128; ++s) {
    int j = 8 * (sub * 128 + s);                   // i-independent sample set
    float t = tdist(px, py, pz, tj[j]);            // 16-lane same-address broadcast
    ins4(t, b0, b1, b2, b3);
  }
  sh[threadIdx.x * 4 + 0] = b0; sh[threadIdx.x * 4 + 1] = b1;
  sh[threadIdx.x * 4 + 2] = b2; sh[threadIdx.x * 4 + 3] = b3;
  __syncthreads();
  for (int st = 8; st > 0; st >>= 1) {
    if (sub < st) {
      int o = ((sub + st) * 16 + i_local) * 4;
#pragma unroll
      for (int m = 0; m < 4; ++m) ins4(sh[o + m], b0, b1, b2, b3);
      sh[threadIdx.x * 4 + 0] = b0; sh[threadIdx.x * 4 + 1] = b1;
      sh[threadIdx.x * 4 + 2] = b2; sh[threadIdx.x * 4 + 3] = b3;
    }
    __syncthreads();
  }
  if (sub == 0) thresh[i] = b3;                    // 4th smallest
}

template <int CHUNKS>
__global__ __launch_bounds__(256) void knn_kernel(const float4* __restrict__ tj,
                                                  const float* __restrict__ pred,
                                                  const float* __restrict__ thresh,
                                                  float2* __restrict__ cand) {
  constexpr int CHUNK   = N_ / CHUNKS;
  constexpr int ITEMS   = 4;
  constexpr int IPG     = 1024;
  constexpr int IGROUPS = N_ / IPG;                // 16
  constexpr int TILE    = (CHUNK < 1024) ? CHUNK : 1024;

  int igrp  = blockIdx.x % IGROUPS;
  int chunk = blockIdx.x / IGROUPS;
  int j0    = chunk * CHUNK;

  __shared__ float4 tile[TILE];
  __shared__ float  tilep[TILE];

  int   idx[ITEMS];
  float px[ITEMS], py[ITEMS], pz[ITEMS], th[ITEMS];
  float b0[ITEMS], b1[ITEMS], b2[ITEMS];
  float q0[ITEMS], q1[ITEMS], q2[ITEMS];
#pragma unroll
  for (int k = 0; k < ITEMS; ++k) {
    int i = igrp * IPG + threadIdx.x + k * 256;
    idx[k] = i;
    float4 ti = tj[i];
    px[k] = -0.5f * ti.x; py[k] = -0.5f * ti.y; pz[k] = -0.5f * ti.z;
    th[k] = thresh[i];
    b0[k] = b1[k] = b2[k] = FLT_MAX;
    q0[k] = q1[k] = q2[k] = 0.f;
  }

  for (int sub = 0; sub < CHUNK; sub += TILE) {
    __syncthreads();
    for (int t = threadIdx.x; t < TILE; t += 256) {
      tile[t]  = tj[j0 + sub + t];
      tilep[t] = pred[j0 + sub + t];
    }
    __syncthreads();
    int jg0 = j0 + sub;
#pragma unroll 4
    for (int jj = 0; jj < TILE; ++jj) {
      float4 c4 = tile[jj];                        // wave-uniform -> LDS broadcast
      int jg = jg0 + jj;
#pragma unroll
      for (int k = 0; k < ITEMS; ++k) {
        float t = tdist(px[k], py[k], pz[k], c4);
        bool hit = (t <= th[k]);
        if (__any(hit)) {                          // ~12% taken -> real wave-level skip
          if (hit && jg != idx[k]) {
            float qw = tilep[jj];
            bool cc0 = t < b0[k], cc1 = t < b1[k], cc2 = t < b2[k];
            if (cc2) {
              float nb2 = cc1 ? b1[k] : t;                  float nq2 = cc1 ? q1[k] : qw;
              float nb1 = cc0 ? b0[k] : (cc1 ? t : b1[k]);  float nq1 = cc0 ? q0[k] : (cc1 ? qw : q1[k]);
              float nb0 = cc0 ? t : b0[k];                  float nq0 = cc0 ? qw : q0[k];
              b0[k] = nb0; b1[k] = nb1; b2[k] = nb2;
              q0[k] = nq0; q1[k] = nq1; q2[k] = nq2;
            }
          }
        }
      }
    }
  }

#pragma unroll
  for (int k = 0; k < ITEMS; ++k) {
    cand[((size_t)chunk * 3 + 0) * N_ + idx[k]] = make_float2(b0[k], q0[k]);
    cand[((size_t)chunk * 3 + 1) * N_ + idx[k]] = make_float2(b1[k], q1[k]);
    cand[((size_t)chunk * 3 + 2) * N_ + idx[k]] = make_float2(b2[k], q2[k]);
  }
}

// 16 i's per block, 16 threads/i; LDS tree merge; per-block partial store. grid 1024.
__global__ __launch_bounds__(256) void merge_kernel(const float* __restrict__ pred,
                                                    const float2* __restrict__ cand,
                                                    int chunks,
                                                    float* __restrict__ pS) {
  __shared__ float2 sh[256 * 3];
  int i_local = threadIdx.x & 15;
  int sub     = threadIdx.x >> 4;
  int i = blockIdx.x * 16 + i_local;

  float b0 = FLT_MAX, b1 = FLT_MAX, b2 = FLT_MAX;
  float q0 = 0.f, q1 = 0.f, q2 = 0.f;
  auto ins = [&](float t, float qw) {
    if (t < b2) {
      bool cc0 = t < b0, cc1 = t < b1;
      float nb2 = cc1 ? b1 : t;               float nq2 = cc1 ? q1 : qw;
      float nb1 = cc0 ? b0 : (cc1 ? t : b1);  float nq1 = cc0 ? q0 : (cc1 ? qw : q1);
      float nb0 = cc0 ? t : b0;               float nq0 = cc0 ? qw : q0;
      b0 = nb0; b1 = nb1; b2 = nb2; q0 = nq0; q1 = nq1; q2 = nq2;
    }
  };
  int cpt = chunks >> 4;
  for (int cc = 0; cc < cpt; ++cc) {
    int c = sub * cpt + cc;
    const float2* basep = cand + (size_t)c * 3 * N_;
#pragma unroll
    for (int m = 0; m < 3; ++m) {
      float2 v = basep[(size_t)m * N_ + i];        // 16 consecutive i -> 128B segments
      ins(v.x, v.y);
    }
  }
  sh[threadIdx.x * 3 + 0] = make_float2(b0, q0);
  sh[threadIdx.x * 3 + 1] = make_float2(b1, q1);
  sh[threadIdx.x * 3 + 2] = make_float2(b2, q2);
  __syncthreads();
  for (int st = 8; st > 0; st >>= 1) {
    if (sub < st) {
      int o = ((sub + st) * 16 + i_local) * 3;
#pragma unroll
      for (int m = 0; m < 3; ++m) { float2 v = sh[o + m]; ins(v.x, v.y); }
      sh[threadIdx.x * 3 + 0] = make_float2(b0, q0);
      sh[threadIdx.x * 3 + 1] = make_float2(b1, q1);
      sh[threadIdx.x * 3 + 2] = make_float2(b2, q2);
    }
    __syncthreads();
  }

  float s = 0.f;
  if (sub == 0) {                                  // tid < 16, all wave 0
    float pi = pred[i];
    s = fabsf(pi - q0) + fabsf(pi - q1) + fabsf(pi - q2);
  }
  if (threadIdx.x < 64) {
    for (int off = 8; off > 0; off >>= 1) s += __shfl_down(s, off);
    if (threadIdx.x == 0) pS[blockIdx.x] = s;      // plain store
  }
}

// single block: sum pA[3][256] + pS[1024], write out[0].
__global__ __launch_bounds__(256) void finalize_kernel(const float* __restrict__ pA,
                                                       const float* __restrict__ pS,
                                                       float* __restrict__ out) {
  __shared__ float wred[4][4];
  int tid = threadIdx.x;
  float s_occ  = pA[tid];
  float s_cons = pA[256 + tid];
  float s_sp   = pA[512 + tid];
  float s_sm   = pS[tid] + pS[256 + tid] + pS[512 + tid] + pS[768 + tid];
  for (int off = 32; off > 0; off >>= 1) {
    s_occ  += __shfl_down(s_occ, off);
    s_cons += __shfl_down(s_cons, off);
    s_sp   += __shfl_down(s_sp, off);
    s_sm   += __shfl_down(s_sm, off);
  }
  if ((tid & 63) == 0) {
    int w = tid >> 6;
    wred[w][0] = s_occ; wred[w][1] = s_cons; wred[w][2] = s_sp; wred[w][3] = s_sm;
  }
  __syncthreads();
  if (tid == 0) {
    float occ  = wred[0][0] + wred[1][0] + wred[2][0] + wred[3][0];
    float cons = wred[0][1] + wred[1][1] + wred[2][1] + wred[3][1];
    float sp   = wred[0][2] + wred[1][2] + wred[2][2] + wred[3][2];
    float sm   = wred[0][3] + wred[1][3] + wred[2][3] + wred[3][3];
    out[0] = OCC_W * (occ / (float)N_)
           + CONS_W * (cons / (float)N_)
           + SPARSE_W * (sp / (float)(N_ * F_))
           + SMOOTH_W * (sm / (float)(N_ * 3));
  }
}

extern "C" void kernel_launch(void* const* d_in, const int* in_sizes, int n_in,
                              void* d_out, int out_size, void* d_ws, size_t ws_size,
                              hipStream_t stream) {
  const float* pred = (const float*)d_in[0];
  const float* targ = (const float*)d_in[1];
  const float* feat = (const float*)d_in[2];
  const float* pts  = (const float*)d_in[3];
  float* out = (float*)d_out;

  char*   ws     = (char*)d_ws;
  float*  pA     = (float*)ws;                       // 3*256 floats
  float*  pS     = (float*)(ws + 3072);              // 1024 floats
  float4* tj     = (float4*)(ws + 8192);
  float*  thresh = (float*)(ws + 8192 + (size_t)N_ * 16);
  float2* cand   = (float2*)(ws + 8192 + (size_t)N_ * 16 + (size_t)N_ * 4);

  reduce_tj_kernel<<<256, 256, 0, stream>>>(pred, targ, feat, pts, pA, tj);
  sample_kernel<<<1024, 256, 0, stream>>>(tj, thresh);

  size_t base = 8192 + (size_t)N_ * 16 + (size_t)N_ * 4;
  auto need = [&](int c) { return base + (size_t)c * 3 * N_ * sizeof(float2); };
  int chunks;
  if      (ws_size >= need(128)) chunks = 128;
  else if (ws_size >= need(64))  chunks = 64;
  else                           chunks = 32;

  if (chunks == 128)     knn_kernel<128><<<16 * 128, 256, 0, stream>>>(tj, pred, thresh, cand);
  else if (chunks == 64) knn_kernel<64><<<16 * 64, 256, 0, stream>>>(tj, pred, thresh, cand);
  else                   knn_kernel<32><<<16 * 32, 256, 0, stream>>>(tj, pred, thresh, cand);

  merge_kernel<<<1024, 256, 0, stream>>>(pred, cand, chunks, pS);
  finalize_kernel<<<1, 256, 0, stream>>>(pA, pS, out);
}

// Round 8
// 136.639 us; speedup vs baseline: 4.3520x; 1.2711x over previous
//
#include <hip/hip_runtime.h>
#include <float.h>
#include <math.h>

// AdvancedLossFunction: total = 1.0*occ + 0.1*smooth + 0.01*sparse + 0.1*cons
// 3 dispatches. 3-NN via branchless packed-key brute force:
//   key(i,j) = float_bits(d2(i,j)) with low 16 mantissa bits replaced by
//              quantize16(pred[j]).  Ordering by key == ordering by d2 at 2^-8
//              relative resolution; payload carries the neighbor's pred.
//   Top-4 keys per i kept with fmin + 3x v_med3_f32 (sorted-insert clamp) —
//   9 flat VALU ops/pair, no branches, no self-check (self d2 ~ 0 is always
//   the minimum key; slots 1..3 after the global merge are the 3 NNs).
//   Accuracy cost: ~1e-4 on the scalar output (threshold 2.1e-2).
// R7 lessons: flat > __any-gated (branch kills scheduling); no contended atomics.

constexpr int   N_ = 16384;
constexpr int   F_ = 64;
constexpr float OCC_W = 1.0f, SMOOTH_W = 0.1f, SPARSE_W = 0.01f, CONS_W = 0.1f;
constexpr float EPS_ = 1e-7f;

// ws layout:
//   0      : float4 part[1024]        (occ, cons, sparse, smooth per merge-block)
//   16384  : float4 cand[CHUNKS][N]   (top-4 packed keys per (chunk, i))

__device__ __forceinline__ void ins4f(float t, float& b0, float& b1, float& b2, float& b3) {
  // maintains b0<=b1<=b2<=b3; med3(a,b,t) with a<=b == clamp(t,a,b) == sorted insert
  float n0 = fminf(b0, t);
  float n1 = __builtin_amdgcn_fmed3f(b0, b1, t);
  float n2 = __builtin_amdgcn_fmed3f(b1, b2, t);
  float n3 = __builtin_amdgcn_fmed3f(b2, b3, t);
  b0 = n0; b1 = n1; b2 = n2; b3 = n3;
}

template <int CHUNKS>
__global__ __launch_bounds__(256) void knn_kernel(const float* __restrict__ pts,
                                                  const float* __restrict__ pred,
                                                  float4* __restrict__ cand) {
  constexpr int CHUNK   = N_ / CHUNKS;             // 256 at CHUNKS=64
  constexpr int TILE    = CHUNK;
  constexpr int ITEMS   = 4;
  constexpr int IPG     = 1024;
  constexpr int IGROUPS = N_ / IPG;                // 16
  int igrp  = blockIdx.x % IGROUPS;
  int chunk = blockIdx.x / IGROUPS;
  int j0    = chunk * CHUNK;

  __shared__ float4   tile[TILE];                  // (-2x,-2y,-2z,|q|^2)
  __shared__ unsigned tileq[TILE];                 // pred quantized to 16 bits

  for (int t = threadIdx.x; t < TILE; t += 256) {
    int j = j0 + t;
    float x = pts[3 * j], y = pts[3 * j + 1], z = pts[3 * j + 2];
    tile[t]  = make_float4(-2.f * x, -2.f * y, -2.f * z, fmaf(x, x, fmaf(y, y, z * z)));
    tileq[t] = (unsigned)fmaf(pred[j], 65535.f, 0.5f);
  }

  float xi[ITEMS], yi[ITEMS], zi[ITEMS], sqi[ITEMS];
  float b0[ITEMS], b1[ITEMS], b2[ITEMS], b3[ITEMS];
#pragma unroll
  for (int k = 0; k < ITEMS; ++k) {
    int i = igrp * IPG + threadIdx.x + k * 256;
    float x = pts[3 * i], y = pts[3 * i + 1], z = pts[3 * i + 2];
    xi[k] = x; yi[k] = y; zi[k] = z;
    sqi[k] = fmaf(x, x, fmaf(y, y, z * z));
    b0[k] = b1[k] = b2[k] = b3[k] = FLT_MAX;
  }
  __syncthreads();

#pragma unroll 4
  for (int jj = 0; jj < TILE; ++jj) {
    float4   q  = tile[jj];                        // wave-uniform -> LDS broadcast
    unsigned pj = tileq[jj];
#pragma unroll
    for (int k = 0; k < ITEMS; ++k) {
      float t  = fmaf(xi[k], q.x, fmaf(yi[k], q.y, fmaf(zi[k], q.z, q.w)));  // -2p.q+|q|^2
      float d2 = t + sqi[k];                       // = |p-q|^2 (+- ulps; self ~ 0)
      float kf = __uint_as_float((__float_as_uint(d2) & 0xFFFF0000u) | pj);
      ins4f(kf, b0[k], b1[k], b2[k], b3[k]);       // 9 flat VALU ops/pair total
    }
  }

#pragma unroll
  for (int k = 0; k < ITEMS; ++k) {
    int i = igrp * IPG + threadIdx.x + k * 256;
    cand[(size_t)chunk * N_ + i] = make_float4(b0[k], b1[k], b2[k], b3[k]);
  }
}

// grid 1024: merges per-chunk top-4s, decodes payload preds -> smoothness,
// plus all scalar reductions (feat float4s covered exactly once). float4 partial/block.
template <int CHUNKS>
__global__ __launch_bounds__(256) void merge_kernel(const float* __restrict__ pred,
                                                    const float* __restrict__ targ,
                                                    const float* __restrict__ feat,
                                                    const float4* __restrict__ cand,
                                                    float4* __restrict__ part) {
  __shared__ float4 sh[256];
  __shared__ float ws4[4][4];
  int tid = threadIdx.x;
  int i_local = tid & 15, sub = tid >> 4;          // 16 i's/block, 16 threads/i
  int i = blockIdx.x * 16 + i_local;

  float4 v = ((const float4*)feat)[blockIdx.x * 256 + tid];
  float s_sp = fabsf(v.x) + fabsf(v.y) + fabsf(v.z) + fabsf(v.w);

  constexpr int CPT = CHUNKS / 16;
  float b0 = FLT_MAX, b1 = FLT_MAX, b2 = FLT_MAX, b3 = FLT_MAX;
  for (int cc = 0; cc < CPT; ++cc) {
    float4 q = cand[(size_t)(sub * CPT + cc) * N_ + i];   // 16 consecutive i -> 256B
    ins4f(q.x, b0, b1, b2, b3);
    ins4f(q.y, b0, b1, b2, b3);
    ins4f(q.z, b0, b1, b2, b3);
    ins4f(q.w, b0, b1, b2, b3);
  }
  sh[tid] = make_float4(b0, b1, b2, b3);
  __syncthreads();
  for (int st = 8; st > 0; st >>= 1) {
    if (sub < st) {
      float4 q = sh[((sub + st) << 4) | i_local];
      ins4f(q.x, b0, b1, b2, b3);
      ins4f(q.y, b0, b1, b2, b3);
      ins4f(q.z, b0, b1, b2, b3);
      ins4f(q.w, b0, b1, b2, b3);
      sh[tid] = make_float4(b0, b1, b2, b3);
    }
    __syncthreads();
  }

  float s_occ = 0.f, s_cons = 0.f, s_sm = 0.f;
  if (sub == 0) {                                  // tid < 16: global top-4 for i
    float pi = pred[i], tg = targ[i];
    float p  = fminf(fmaxf(pi, EPS_), 1.0f - EPS_);
    s_occ = -(tg * __logf(p) + (1.0f - tg) * __logf(1.0f - p));
    float d = pi - tg;
    s_cons = d * d;
    constexpr float inv = 1.0f / 65535.f;          // b0 = self (d2~0, min); NNs = b1..b3
    float p1 = (float)(__float_as_uint(b1) & 0xFFFFu) * inv;
    float p2 = (float)(__float_as_uint(b2) & 0xFFFFu) * inv;
    float p3 = (float)(__float_as_uint(b3) & 0xFFFFu) * inv;
    s_sm = fabsf(pi - p1) + fabsf(pi - p2) + fabsf(pi - p3);
  }

  for (int off = 32; off > 0; off >>= 1) {         // zeros on lanes >=16 keep sums exact
    s_sp   += __shfl_down(s_sp, off);
    s_occ  += __shfl_down(s_occ, off);
    s_cons += __shfl_down(s_cons, off);
    s_sm   += __shfl_down(s_sm, off);
  }
  if ((tid & 63) == 0) {
    int w = tid >> 6;
    ws4[w][0] = s_occ; ws4[w][1] = s_cons; ws4[w][2] = s_sp; ws4[w][3] = s_sm;
  }
  __syncthreads();
  if (tid == 0) {
    part[blockIdx.x] = make_float4(ws4[0][0] + ws4[1][0] + ws4[2][0] + ws4[3][0],
                                   ws4[0][1] + ws4[1][1] + ws4[2][1] + ws4[3][1],
                                   ws4[0][2] + ws4[1][2] + ws4[2][2] + ws4[3][2],
                                   ws4[0][3] + ws4[1][3] + ws4[2][3] + ws4[3][3]);
  }
}

__global__ __launch_bounds__(256) void finalize_kernel(const float4* __restrict__ part,
                                                       float* __restrict__ out) {
  __shared__ float ws4[4][4];
  int tid = threadIdx.x;
  float4 a = part[tid], b = part[256 + tid], c = part[512 + tid], d = part[768 + tid];
  float o  = a.x + b.x + c.x + d.x;
  float cn = a.y + b.y + c.y + d.y;
  float sp = a.z + b.z + c.z + d.z;
  float sm = a.w + b.w + c.w + d.w;
  for (int off = 32; off > 0; off >>= 1) {
    o  += __shfl_down(o, off);
    cn += __shfl_down(cn, off);
    sp += __shfl_down(sp, off);
    sm += __shfl_down(sm, off);
  }
  if ((tid & 63) == 0) {
    int w = tid >> 6;
    ws4[w][0] = o; ws4[w][1] = cn; ws4[w][2] = sp; ws4[w][3] = sm;
  }
  __syncthreads();
  if (tid == 0) {
    float occ  = ws4[0][0] + ws4[1][0] + ws4[2][0] + ws4[3][0];
    float cons = ws4[0][1] + ws4[1][1] + ws4[2][1] + ws4[3][1];
    float spar = ws4[0][2] + ws4[1][2] + ws4[2][2] + ws4[3][2];
    float smoo = ws4[0][3] + ws4[1][3] + ws4[2][3] + ws4[3][3];
    out[0] = OCC_W * (occ / (float)N_)
           + CONS_W * (cons / (float)N_)
           + SPARSE_W * (spar / (float)(N_ * F_))
           + SMOOTH_W * (smoo / (float)(N_ * 3));
  }
}

extern "C" void kernel_launch(void* const* d_in, const int* in_sizes, int n_in,
                              void* d_out, int out_size, void* d_ws, size_t ws_size,
                              hipStream_t stream) {
  const float* pred = (const float*)d_in[0];
  const float* targ = (const float*)d_in[1];
  const float* feat = (const float*)d_in[2];
  const float* pts  = (const float*)d_in[3];
  float* out = (float*)d_out;

  char*   ws   = (char*)d_ws;
  float4* part = (float4*)ws;                      // 1024 * 16B = 16 KB
  float4* cand = (float4*)(ws + 16384);

  size_t need64 = 16384 + (size_t)64 * N_ * 16;    // 16.8 MB
  if (ws_size >= need64) {
    knn_kernel<64><<<16 * 64, 256, 0, stream>>>(pts, pred, cand);
    merge_kernel<64><<<1024, 256, 0, stream>>>(pred, targ, feat, cand, part);
  } else {
    knn_kernel<32><<<16 * 32, 256, 0, stream>>>(pts, pred, cand);
    merge_kernel<32><<<1024, 256, 0, stream>>>(pred, targ, feat, cand, part);
  }
  finalize_kernel<<<1, 256, 0, stream>>>(part, out);
}